// Round 6
// baseline (731.987 us; speedup 1.0000x reference)
//
#include <hip/hip_runtime.h>
#include <hip/hip_bf16.h>
#include <math.h>

// Problem constants (fixed by setup_inputs)
#define BB 4
#define NN 16384
#define SS 4096
#define D1 128
#define D2 256
#define C1 256   // mlp[0]
#define C2 128   // mlp[1]
#define MTOT (BB*NN)   // 65536

// R13 grid-kNN constants (Morton-order sort; exact conservative pruning)
#define GC 32                  // cells per axis
#define NCELL (GC*GC*GC)       // 32768 Morton bins
#define GLO (-8.0f)            // grid origin
#define GSC 2.0f               // 1/h, h = 0.5
#define GSZ 64                 // candidates per group (= wave size)
#define NG  (SS/GSZ)           // 64 groups per batch
#define SLACK 1e-3f            // >> all fp rounding in d vs bound

typedef _Float16 f16x8 __attribute__((ext_vector_type(8)));
typedef float f32x4  __attribute__((ext_vector_type(4)));

#define LPAD 40            // LDS row stride in fp16 elems (80B, 16B-aligned)

__device__ __forceinline__ unsigned expand5(unsigned v) {
    v &= 31u;
    v = (v | (v << 8)) & 0x0100Fu;
    v = (v | (v << 4)) & 0x010C3u;
    v = (v | (v << 2)) & 0x09249u;
    return v;
}
__device__ __forceinline__ int morton_of(float x, float y, float z) {
    int cx = (int)floorf((x - GLO) * GSC);
    int cy = (int)floorf((y - GLO) * GSC);
    int cz = (int)floorf((z - GLO) * GSC);
    cx = min(max(cx, 0), GC - 1);
    cy = min(max(cy, 0), GC - 1);
    cz = min(max(cz, 0), GC - 1);
    return (int)((expand5((unsigned)cz) << 2) | (expand5((unsigned)cy) << 1) | expand5((unsigned)cx));
}

// ---------------------------------------------------------------------------
// Convert W1, W2 to fp16 (RNE) once.
// ---------------------------------------------------------------------------
__global__ __launch_bounds__(256) void wcvt_kernel(
    const float* __restrict__ W1, const float* __restrict__ W2,
    _Float16* __restrict__ W1c, _Float16* __restrict__ W2c)
{
    int i = blockIdx.x * 256 + threadIdx.x;
    if (i < C1 * (D1 + D2)) W1c[i] = (_Float16)W1[i];
    if (i < C2 * C1)        W2c[i] = (_Float16)W2[i];
}

// ---------------------------------------------------------------------------
// R13: combined Morton histogram for candidates (xyz2) and queries (xyz1).
// Bin choice affects PERF only; correctness rests on exact bound + lex cmp.
// ---------------------------------------------------------------------------
__global__ __launch_bounds__(256) void histo_kernel(
    const float* __restrict__ xyz2, const float* __restrict__ xyz1,
    unsigned* __restrict__ histC, unsigned* __restrict__ histQ)
{
    int i = blockIdx.x * 256 + threadIdx.x;
    if (i < BB * SS) {
        int b = i >> 12;
        float x = xyz2[(size_t)i*3+0], y = xyz2[(size_t)i*3+1], z = xyz2[(size_t)i*3+2];
        atomicAdd(&histC[(size_t)b * NCELL + morton_of(x, y, z)], 1u);
    } else {
        int j = i - BB * SS;
        int b = j >> 14;
        float x = xyz1[(size_t)j*3+0], y = xyz1[(size_t)j*3+1], z = xyz1[(size_t)j*3+2];
        atomicAdd(&histQ[(size_t)b * NCELL + morton_of(x, y, z)], 1u);
    }
}

// blocks 0..3: candidate hist -> startC + nextC ; 4..7: query hist -> nextQ
// Parallel exclusive scan (Hillis-Steele over 256 per-thread partials).
__global__ __launch_bounds__(256) void scan_kernel(
    const unsigned* __restrict__ histC, unsigned* __restrict__ startC,
    unsigned* __restrict__ nextC,
    const unsigned* __restrict__ histQ, unsigned* __restrict__ nextQ)
{
    __shared__ unsigned ps[256];
    const int blk = blockIdx.x;
    const bool isC = blk < 4;
    const int b = isC ? blk : blk - 4;
    const unsigned* h = (isC ? histC : histQ) + (size_t)b * NCELL;
    unsigned* st = isC ? startC + (size_t)b * NCELL : nullptr;
    unsigned* nx = (isC ? nextC : nextQ) + (size_t)b * NCELL;
    const int tid = threadIdx.x;
    const int PB = NCELL / 256;        // 128
    unsigned loc = 0;
    for (int i = 0; i < PB; ++i) loc += h[tid * PB + i];
    ps[tid] = loc;
    __syncthreads();
#pragma unroll
    for (int d = 1; d < 256; d <<= 1) {
        unsigned v = (tid >= d) ? ps[tid - d] : 0u;
        __syncthreads();
        ps[tid] += v;
        __syncthreads();
    }
    unsigned run = ps[tid] - loc;      // exclusive prefix
    for (int i = 0; i < PB; ++i) {
        unsigned c = h[tid * PB + i];
        if (st) st[tid * PB + i] = run;
        nx[tid * PB + i] = run;
        run += c;
    }
}

// Combined scatter: candidates packed {-2x,-2y,-2z,||p||^2} (exact pow2
// scaling -> d formula BIT-EXACT vs reference), queries -> qperm.
__global__ __launch_bounds__(256) void scatter_kernel(
    const float* __restrict__ xyz2, const float* __restrict__ xyz1,
    unsigned* __restrict__ nextC, unsigned* __restrict__ nextQ,
    float4* __restrict__ sPk, unsigned short* __restrict__ sIdx,
    int* __restrict__ qperm)
{
#pragma clang fp contract(off)
    int i = blockIdx.x * 256 + threadIdx.x;
    if (i < BB * SS) {
        int b = i >> 12;
        int s = i & (SS - 1);
        float px = xyz2[(size_t)i*3+0], py = xyz2[(size_t)i*3+1], pz = xyz2[(size_t)i*3+2];
        int c = morton_of(px, py, pz);
        unsigned pos = atomicAdd(&nextC[(size_t)b * NCELL + c], 1u);
        float pp = (px*px + py*py) + pz*pz;
        sPk[(size_t)b * SS + pos] = make_float4(-2.0f*px, -2.0f*py, -2.0f*pz, pp);
        sIdx[(size_t)b * SS + pos] = (unsigned short)s;
    } else {
        int j = i - BB * SS;
        int b = j >> 14;
        float x = xyz1[(size_t)j*3+0], y = xyz1[(size_t)j*3+1], z = xyz1[(size_t)j*3+2];
        int c = morton_of(x, y, z);
        unsigned pos = atomicAdd(&nextQ[(size_t)b * NCELL + c], 1u);
        qperm[(size_t)b * NN + pos] = j;
    }
}

// AABB per group of 64 (one wave per group; shfl_xor reduce).
// Coords recovered exactly: x = -0.5 * stored.
__global__ __launch_bounds__(64) void aabb_kernel(
    const float4* __restrict__ sPk, float4* __restrict__ aabb)
{
    int gid = blockIdx.x;              // BB*NG groups
    int b = gid >> 6, g = gid & (NG - 1);
    int lane = threadIdx.x;
    float4 p = sPk[(size_t)b * SS + g * GSZ + lane];
    float x = -0.5f * p.x, y = -0.5f * p.y, z = -0.5f * p.z;
    float mnx = x, mny = y, mnz = z, mxx = x, mxy = y, mxz = z;
#pragma unroll
    for (int d = 1; d < 64; d <<= 1) {
        mnx = fminf(mnx, __shfl_xor(mnx, d)); mxx = fmaxf(mxx, __shfl_xor(mxx, d));
        mny = fminf(mny, __shfl_xor(mny, d)); mxy = fmaxf(mxy, __shfl_xor(mxy, d));
        mnz = fminf(mnz, __shfl_xor(mnz, d)); mxz = fmaxf(mxz, __shfl_xor(mxz, d));
    }
    if (lane == 0) {
        aabb[(size_t)gid * 2 + 0] = make_float4(mnx, mny, mnz, 0.0f);
        aabb[(size_t)gid * 2 + 1] = make_float4(mxx, mxy, mxz, 0.0f);
    }
}

// ---------------------------------------------------------------------------
// R13 grid 3-NN: one wave per 64 Morton-sorted queries (spatially compact).
// Scan the 64 Morton candidate groups in seed-centered zigzag; skip a group
// when the exact conservative AABB bound exceeds e2+SLACK for ALL lanes.
// Taken groups: each lane holds one candidate (coalesced 16B), broadcast
// via readlane (uniform t -> SGPR operands; no LDS, no barriers).
// Selection = lexicographic (d, s) == lax.top_k stable order (verified R5).
// HARD CONSTRAINT (R7): distance formula and comparison are exact.
// ---------------------------------------------------------------------------
__global__ __launch_bounds__(64) void knn3_grid_kernel(
    const float* __restrict__ xyz1, const float4* __restrict__ sPk,
    const unsigned short* __restrict__ sIdx, const unsigned* __restrict__ cellStartC,
    const float4* __restrict__ aabb, const int* __restrict__ qperm,
    int* __restrict__ idx_out, float* __restrict__ w_out)
{
#pragma clang fp contract(off)
    const int lane = threadIdx.x;
    const int b = blockIdx.x >> 8;                 // 256 waves per batch
    const int qpos = (blockIdx.x & 255) * 64 + lane;

    const int qid = qperm[(size_t)b * NN + qpos];  // global m
    const float qx = xyz1[(size_t)qid*3+0];
    const float qy = xyz1[(size_t)qid*3+1];
    const float qz = xyz1[(size_t)qid*3+2];
    const float qq = (qx*qx + qy*qy) + qz*qz;

    int g0 = min((int)(cellStartC[(size_t)b * NCELL + morton_of(qx, qy, qz)] >> 6), NG - 1);
    g0 = __builtin_amdgcn_readfirstlane(g0);       // wave-uniform seed (perf only)

    float e0 = 3.4e38f, e1 = 3.4e38f, e2 = 3.4e38f;
    int   j0 = 0, j1 = 0, j2 = 0;

    const float4* boxp = aabb + (size_t)b * NG * 2;
    const float4* pkp  = sPk  + (size_t)b * SS;
    const unsigned short* sidp = sIdx + (size_t)b * SS;

    for (int k = 0; k < NG; ++k) {
        int off = (k + 1) >> 1;
        if (k & 1) off = -off;
        int g = (g0 + off) & (NG - 1);

        float4 mn = boxp[g*2], mx = boxp[g*2+1];
        float dx = fmaxf(fmaxf(mn.x - qx, qx - mx.x), 0.0f);
        float dy = fmaxf(fmaxf(mn.y - qy, qy - mx.y), 0.0f);
        float dz = fmaxf(fmaxf(mn.z - qz, qz - mx.z), 0.0f);
        float bnd = (dx*dx + dy*dy) + dz*dz;
        bool need = bnd < e2 + SLACK;              // e2 sentinel-huge early -> true
        if (__any(need)) {
            const int gb = g * GSZ;
            float4 P = pkp[gb + lane];             // coalesced: lane's candidate
            int    S = (int)sidp[gb + lane];
#pragma unroll 4
            for (int t = 0; t < GSZ; ++t) {
                float px = __uint_as_float(__builtin_amdgcn_readlane(__float_as_uint(P.x), t));
                float py = __uint_as_float(__builtin_amdgcn_readlane(__float_as_uint(P.y), t));
                float pz = __uint_as_float(__builtin_amdgcn_readlane(__float_as_uint(P.z), t));
                float pw = __uint_as_float(__builtin_amdgcn_readlane(__float_as_uint(P.w), t));
                int   s  = __builtin_amdgcn_readlane(S, t);
                float cr2 = (qx*px + qy*py) + qz*pz;      // == -2*cr exactly
                float d = (qq + cr2) + pw;
                d = fmaxf(d, 0.0f);
                bool c0 = (d < e0) || (d == e0 && s < j0);
                bool c1 = (d < e1) || (d == e1 && s < j1);
                bool c2 = (d < e2) || (d == e2 && s < j2);
                j2 = c1 ? j1 : (c2 ? s : j2);
                e2 = c1 ? e1 : (c2 ? d : e2);
                j1 = c0 ? j0 : (c1 ? s : j1);
                e1 = c0 ? e0 : (c1 ? d : e1);
                j0 = c0 ? s : j0;
                e0 = c0 ? d : e0;
            }
        }
    }

    float r0 = 1.0f / (e0 + 1e-8f);
    float r1 = 1.0f / (e1 + 1e-8f);
    float r2 = 1.0f / (e2 + 1e-8f);
    float inv = 1.0f / ((r0 + r1) + r2);
    idx_out[(size_t)qid*3+0] = b * SS + j0;
    idx_out[(size_t)qid*3+1] = b * SS + j1;
    idx_out[(size_t)qid*3+2] = b * SS + j2;
    w_out[(size_t)qid*3+0] = r0 * inv;
    w_out[(size_t)qid*3+1] = r1 * inv;
    w_out[(size_t)qid*3+2] = r2 * inv;
}

// ---------------------------------------------------------------------------
// fp16 MFMA GEMM, LDS double-buffered with ONE barrier per k-iter.
// C[M x N] = op(A[M x K]) @ W[N x K]^T (+ bias).
// Tile 64(M) x 128(N), 4 waves of 32x64, k-chunk 32 (16x16x32 f16 MFMA).
// ---------------------------------------------------------------------------
template<int K, typename AT, typename OT, bool BN_A, bool FUSE_STATS>
__global__ __launch_bounds__(256, 4) void gemm_mfma_kernel(
    const AT* __restrict__ A, int lda,
    const _Float16* __restrict__ W, int ldw,
    OT* __restrict__ C, int ldc,
    const float* __restrict__ bias,
    const float* __restrict__ scaleA, const float* __restrict__ shiftA,
    float* __restrict__ sumO, float* __restrict__ sqO)
{
    __shared__ _Float16 Ash[2][64 * LPAD];     // 2 x 5 KB
    __shared__ _Float16 Bsh[2][128 * LPAD];    // 2 x 10 KB

    const int tid = threadIdx.x;
    const int m0 = blockIdx.x * 64;
    const int n0 = blockIdx.y * 128;
    const int wave = tid >> 6, lane = tid & 63;
    const int ln = lane & 15, q4 = lane >> 4;
    const int wm = wave & 1, wn = wave >> 1;

    const int ar = tid >> 2, ak = (tid & 3) * 8;   // A staging: 64 rows x 32k
    const int br = tid >> 1, bk = (tid & 1) * 16;  // B staging: 128 rows x 32k

    f32x4 acc[2][4] = {};

    float  avF[8];      // used when AT == float
    f16x8  avH;         // used when AT == _Float16
    f16x8  bvA[2];

    {   // prologue prefetch k0 = 0
        if constexpr (__is_same(AT, float)) {
            const float* ap = A + (size_t)(m0 + ar) * lda + ak;
            *(float4*)&avF[0] = *(const float4*)ap;
            *(float4*)&avF[4] = *(const float4*)(ap + 4);
        } else {
            avH = *(const f16x8*)(A + (size_t)(m0 + ar) * lda + ak);
        }
        const _Float16* bp = W + (size_t)(n0 + br) * ldw + bk;
        bvA[0] = *(const f16x8*)bp;
        bvA[1] = *(const f16x8*)(bp + 8);
    }

    for (int k0 = 0; k0 < K; k0 += 32) {
        const int buf = (k0 >> 5) & 1;

        // ---- transform + store staged regs to LDS[buf] ----
        {
            float av[8];
            if constexpr (__is_same(AT, float)) {
#pragma unroll
                for (int i = 0; i < 8; ++i) av[i] = avF[i];
            } else {
#pragma unroll
                for (int i = 0; i < 8; ++i) av[i] = (float)avH[i];
            }
            if (BN_A) {
#pragma unroll
                for (int i = 0; i < 8; ++i) {
                    float sc = scaleA[k0 + ak + i];
                    float sh = shiftA[k0 + ak + i];
                    av[i] = fmaxf(av[i] * sc + sh, 0.0f);
                }
            }
            f16x8 vh;
#pragma unroll
            for (int i = 0; i < 8; ++i) vh[i] = (_Float16)av[i];
            *(f16x8*)&Ash[buf][ar * LPAD + ak] = vh;
            *(f16x8*)&Bsh[buf][br * LPAD + bk]     = bvA[0];
            *(f16x8*)&Bsh[buf][br * LPAD + bk + 8] = bvA[1];
        }
        __syncthreads();    // single barrier: writers of buf done; dbuf makes it safe

        // ---- issue next chunk's global loads (overlap with MFMA below) ----
        if (k0 + 32 < K) {
            if constexpr (__is_same(AT, float)) {
                const float* ap = A + (size_t)(m0 + ar) * lda + (k0 + 32) + ak;
                *(float4*)&avF[0] = *(const float4*)ap;
                *(float4*)&avF[4] = *(const float4*)(ap + 4);
            } else {
                avH = *(const f16x8*)(A + (size_t)(m0 + ar) * lda + (k0 + 32) + ak);
            }
            const _Float16* bp = W + (size_t)(n0 + br) * ldw + (k0 + 32) + bk;
            bvA[0] = *(const f16x8*)bp;
            bvA[1] = *(const f16x8*)(bp + 8);
        }

        // ---- fragments + MFMA ----
        f16x8 af[2];
#pragma unroll
        for (int mi = 0; mi < 2; ++mi) {
            int arow = wm * 32 + mi * 16 + ln;
            af[mi] = *(const f16x8*)&Ash[buf][arow * LPAD + q4 * 8];
        }
        f16x8 bf[4];
#pragma unroll
        for (int ni = 0; ni < 4; ++ni) {
            int brow = wn * 64 + ni * 16 + ln;
            bf[ni] = *(const f16x8*)&Bsh[buf][brow * LPAD + q4 * 8];
        }
#pragma unroll
        for (int mi = 0; mi < 2; ++mi)
#pragma unroll
            for (int ni = 0; ni < 4; ++ni)
                acc[mi][ni] = __builtin_amdgcn_mfma_f32_16x16x32_f16(af[mi], bf[ni], acc[mi][ni], 0, 0, 0);
    }

    // ---- epilogue ----  C/D layout: col = ln, row = q4*4 + r  (m89/m91)
#pragma unroll
    for (int ni = 0; ni < 4; ++ni) {
        int col = n0 + wn * 64 + ni * 16 + ln;
        float vb = bias ? bias[col] : 0.0f;
        float s = 0.0f, s2 = 0.0f;
#pragma unroll
        for (int mi = 0; mi < 2; ++mi) {
#pragma unroll
            for (int r = 0; r < 4; ++r) {
                int row_g = m0 + wm * 32 + mi * 16 + q4 * 4 + r;
                float v = acc[mi][ni][r] + vb;
                C[(size_t)row_g * ldc + col] = (OT)v;
                s += v; s2 += v * v;
            }
        }
        if (FUSE_STATS) {
            s  += __shfl_xor(s, 16);  s  += __shfl_xor(s, 32);
            s2 += __shfl_xor(s2, 16); s2 += __shfl_xor(s2, 32);
            if (q4 == 0) {
                atomicAdd(&sumO[col], s);
                atomicAdd(&sqO[col], s2);
            }
        }
    }
}

// ---------------------------------------------------------------------------
// Dedicated interp + bias + BN1-stats kernel.
// y1[m, :] = temp[m, :] + wa*P2[ia, :] + wb*P2[ib, :] + wc*P2[ic, :] + b1
// ---------------------------------------------------------------------------
__global__ __launch_bounds__(256, 8) void interp_stats_kernel(
    const float* __restrict__ temp,     // [MTOT x C1] fp32 gemm result
    const _Float16* __restrict__ P2,    // [BB*SS x C1] f16
    const int* __restrict__ idx3, const float* __restrict__ w3,
    const float* __restrict__ bias,
    _Float16* __restrict__ Y,           // [MTOT x C1] f16
    float* __restrict__ sumO, float* __restrict__ sqO)
{
    __shared__ float sred[2 * C1];      // 512 floats: [sum | sumsq]
    const int tid = threadIdx.x;
    const int sl  = tid & 31;           // col slice (8 cols)
    const int rg  = tid >> 5;           // 0..7
    const int m0  = blockIdx.x * 32;

    sred[tid] = 0.0f; sred[tid + 256] = 0.0f;
    __syncthreads();

    float bv[8];
    *(float4*)&bv[0] = *(const float4*)(bias + sl * 8);
    *(float4*)&bv[4] = *(const float4*)(bias + sl * 8 + 4);

    float sAcc[8]  = {0.f,0.f,0.f,0.f,0.f,0.f,0.f,0.f};
    float s2Acc[8] = {0.f,0.f,0.f,0.f,0.f,0.f,0.f,0.f};

#pragma unroll
    for (int rr = 0; rr < 4; ++rr) {
        const int row = m0 + rg * 4 + rr;
        const int*   ip = idx3 + (size_t)row * 3;
        const float* wp = w3   + (size_t)row * 3;
        int   ia = ip[0], ib = ip[1], ic = ip[2];
        float wa = wp[0], wb = wp[1], wc = wp[2];

        float av[8];
        const float* tp = temp + (size_t)row * C1 + sl * 8;
        *(float4*)&av[0] = *(const float4*)tp;
        *(float4*)&av[4] = *(const float4*)(tp + 4);
        f16x8 pa = *(const f16x8*)(P2 + (size_t)ia * C1 + sl * 8);
        f16x8 pb = *(const f16x8*)(P2 + (size_t)ib * C1 + sl * 8);
        f16x8 pc = *(const f16x8*)(P2 + (size_t)ic * C1 + sl * 8);

        f16x8 outv;
#pragma unroll
        for (int i = 0; i < 8; ++i) {
            float v = av[i];
            v += wa * (float)pa[i];
            v += wb * (float)pb[i];
            v += wc * (float)pc[i];
            v += bv[i];
            outv[i] = (_Float16)v;
            sAcc[i]  += v;
            s2Acc[i] += v * v;
        }
        *(f16x8*)(Y + (size_t)row * C1 + sl * 8) = outv;
    }

#pragma unroll
    for (int i = 0; i < 8; ++i) {
        atomicAdd(&sred[sl * 8 + i],       sAcc[i]);
        atomicAdd(&sred[256 + sl * 8 + i], s2Acc[i]);
    }
    __syncthreads();
    atomicAdd(&sumO[tid], sred[tid]);
    atomicAdd(&sqO[tid],  sred[tid + 256]);
}

// ---------------------------------------------------------------------------
__global__ void finalize_kernel(
    const float* __restrict__ sum, const float* __restrict__ sumsq,
    const float* __restrict__ g, const float* __restrict__ beta,
    int M, int C, float* __restrict__ scale, float* __restrict__ shift)
{
    int c = threadIdx.x;
    if (c >= C) return;
    float invM = 1.0f / (float)M;
    float mean = sum[c] * invM;
    float var = fmaxf(sumsq[c] * invM - mean * mean, 0.0f);
    float rstd = 1.0f / sqrtf(var + 1e-5f);
    float sc = g[c] * rstd;
    scale[c] = sc;
    shift[c] = beta[c] - mean * sc;
}

__global__ __launch_bounds__(256) void bnrelu_kernel(
    float* __restrict__ X, int total4, int C,
    const float* __restrict__ scale, const float* __restrict__ shift)
{
    int i = blockIdx.x * 256 + threadIdx.x;
    if (i >= total4) return;
    float4 v = ((const float4*)X)[i];
    int c = (i * 4) & (C - 1);      // C pow2, 4 | C -> no wrap within the 4
    v.x = fmaxf(v.x * scale[c+0] + shift[c+0], 0.0f);
    v.y = fmaxf(v.y * scale[c+1] + shift[c+1], 0.0f);
    v.z = fmaxf(v.z * scale[c+2] + shift[c+2], 0.0f);
    v.w = fmaxf(v.w * scale[c+3] + shift[c+3], 0.0f);
    ((float4*)X)[i] = v;
}

// ---------------------------------------------------------------------------
extern "C" void kernel_launch(void* const* d_in, const int* in_sizes, int n_in,
                              void* d_out, int out_size, void* d_ws, size_t ws_size,
                              hipStream_t stream) {
    const float* xyz1    = (const float*)d_in[0];
    const float* xyz2    = (const float*)d_in[1];
    const float* points1 = (const float*)d_in[2];
    const float* points2 = (const float*)d_in[3];
    const float* W1      = (const float*)d_in[4];
    const float* b1      = (const float*)d_in[5];
    const float* g1      = (const float*)d_in[6];
    const float* beta1   = (const float*)d_in[7];
    const float* W2      = (const float*)d_in[8];
    const float* b2      = (const float*)d_in[9];
    const float* g2      = (const float*)d_in[10];
    const float* beta2   = (const float*)d_in[11];
    float* out = (float*)d_out;

    // ws layout (byte offsets, 16B-aligned)
    char* ws = (char*)d_ws;
    size_t off = 0;
    int*   idx = (int*)(ws + off);            off += (size_t)MTOT*3*4;
    float* w   = (float*)(ws + off);          off += (size_t)MTOT*3*4;
    _Float16* P2h = (_Float16*)(ws + off);    off += (size_t)BB*SS*C1*2;    // 8 MB
    _Float16* y1h = (_Float16*)(ws + off);    off += (size_t)MTOT*C1*2;     // 32 MB
    float* stats = (float*)(ws + off);        off += 2048*4;
    float* sum1 = stats;            // 256
    float* sq1  = stats + 256;      // 256
    float* sum2 = stats + 512;      // 128
    float* sq2  = stats + 640;      // 128
    float* scale1 = stats + 768;    // 256
    float* shift1 = stats + 1024;   // 256
    float* scale2 = stats + 1280;   // 128
    float* shift2 = stats + 1408;   // 128
    _Float16* W1c = (_Float16*)(ws + off);    off += (size_t)C1*(D1+D2)*2;
    _Float16* W2c = (_Float16*)(ws + off);    off += (size_t)C2*C1*2;
    off = (off + 255) & ~(size_t)255;
    float* tempf = (float*)(ws + off);        off += (size_t)MTOT*C1*4;     // 64 MB

    // R13 sort-pipeline arrays alias the y1h region (32 MB; y1h is written
    // later, by interp_stats_kernel, after all knn consumers are done).
    char* al = (char*)y1h;
    size_t ao = 0;
    float4* sPk = (float4*)(al + ao);                 ao += (size_t)BB*SS*16;        // 256 KB
    unsigned short* sIdx = (unsigned short*)(al+ao);  ao += (size_t)BB*SS*2;         // 32 KB
    int* qperm = (int*)(al + ao);                     ao += (size_t)BB*NN*4;         // 256 KB
    unsigned* histC = (unsigned*)(al + ao);           ao += (size_t)BB*NCELL*4;      // 512 KB
    unsigned* histQ = (unsigned*)(al + ao);           ao += (size_t)BB*NCELL*4;      // 512 KB
    unsigned* startC = (unsigned*)(al + ao);          ao += (size_t)BB*NCELL*4;      // 512 KB
    unsigned* nextC = (unsigned*)(al + ao);           ao += (size_t)BB*NCELL*4;      // 512 KB
    unsigned* nextQ = (unsigned*)(al + ao);           ao += (size_t)BB*NCELL*4;      // 512 KB
    float4* aabb = (float4*)(al + ao);                ao += (size_t)BB*NG*2*16;      // 8 KB

    hipMemsetAsync(stats, 0, 768 * sizeof(float), stream);
    hipMemsetAsync(histC, 0, (size_t)BB * NCELL * 4 * 2, stream);  // histC + histQ

    wcvt_kernel<<<(C1*(D1+D2))/256, 256, 0, stream>>>(W1, W2, W1c, W2c);

    // ---- Morton sort pipeline (merged launches) ----
    histo_kernel<<<(BB*(SS+NN))/256, 256, 0, stream>>>(xyz2, xyz1, histC, histQ);
    scan_kernel<<<8, 256, 0, stream>>>(histC, startC, nextC, histQ, nextQ);
    scatter_kernel<<<(BB*(SS+NN))/256, 256, 0, stream>>>(
        xyz2, xyz1, nextC, nextQ, sPk, sIdx, qperm);
    aabb_kernel<<<BB*NG, 64, 0, stream>>>(sPk, aabb);

    // ---- grid 3-NN ----
    knn3_grid_kernel<<<MTOT/64, 64, 0, stream>>>(
        xyz1, sPk, sIdx, startC, aabb, qperm, idx, w);

    // P2 = points2 @ W1[:,128:]^T   [B*S x 256], K=256, f16 out
    gemm_mfma_kernel<256, float, _Float16, false, false>
        <<<dim3((BB*SS)/64, C1/128), 256, 0, stream>>>(
        points2, D2, W1c + D1, D1 + D2, P2h, C1,
        nullptr, nullptr, nullptr, nullptr, nullptr);

    // temp = points1 @ W1[:,:128]^T   (plain GEMM, fp32 out, no fusion)
    gemm_mfma_kernel<128, float, float, false, false>
        <<<dim3(MTOT/64, C1/128), 256, 0, stream>>>(
        points1, D1, W1c, D1 + D2, tempf, C1,
        nullptr, nullptr, nullptr, nullptr, nullptr);

    // y1 = temp + interp(P2) + b1  (f16 out) + BN1 stats from fp32
    interp_stats_kernel<<<MTOT/32, 256, 0, stream>>>(
        tempf, P2h, idx, w, b1, y1h, sum1, sq1);

    finalize_kernel<<<1, 256, 0, stream>>>(sum1, sq1, g1, beta1, MTOT, C1, scale1, shift1);

    // out = relu(bn1(y1)) @ W2^T + b2;  fp32 out; fused BN2 stats
    gemm_mfma_kernel<256, _Float16, float, true, true>
        <<<dim3(MTOT/64, C2/128), 256, 0, stream>>>(
        y1h, C1, W2c, C1, out, C2,
        b2, scale1, shift1, sum2, sq2);

    finalize_kernel<<<1, 128, 0, stream>>>(sum2, sq2, g2, beta2, MTOT, C2, scale2, shift2);
    bnrelu_kernel<<<(MTOT*C2/4)/256, 256, 0, stream>>>(out, MTOT*C2/4, C2, scale2, shift2);
}

// Round 7
// 533.205 us; speedup vs baseline: 1.3728x; 1.3728x over previous
//
#include <hip/hip_runtime.h>
#include <hip/hip_bf16.h>
#include <math.h>

// Problem constants (fixed by setup_inputs)
#define BB 4
#define NN 16384
#define SS 4096
#define D1 128
#define D2 256
#define C1 256   // mlp[0]
#define C2 128   // mlp[1]
#define MTOT (BB*NN)   // 65536

// knn: R3 partial/merge engine (8 blocks/CU throughput-proven) + R13 Morton
// sort + R14 ub-based conservative chunk pruning.
#define QPT 2              // queries per thread
#define SCH 256            // candidates per chunk (4KB LDS)
#define NCH (SS/SCH)       // 16 chunks per batch

// Morton binning (perf only; correctness rests on exact bound + lex cmp)
#define GC 32
#define NCELL (GC*GC*GC)   // 32768
#define GLO (-8.0f)
#define GSC 2.0f
#define SLACK 1e-3f        // >> all fp rounding in d vs bound
#define SENT_J 0x7FFFFFFF

typedef _Float16 f16x8 __attribute__((ext_vector_type(8)));
typedef float f32x4  __attribute__((ext_vector_type(4)));

#define LPAD 40            // LDS row stride in fp16 elems (80B, 16B-aligned)

__device__ __forceinline__ unsigned expand5(unsigned v) {
    v &= 31u;
    v = (v | (v << 8)) & 0x0100Fu;
    v = (v | (v << 4)) & 0x010C3u;
    v = (v | (v << 2)) & 0x09249u;
    return v;
}
__device__ __forceinline__ int morton_of(float x, float y, float z) {
    int cx = (int)floorf((x - GLO) * GSC);
    int cy = (int)floorf((y - GLO) * GSC);
    int cz = (int)floorf((z - GLO) * GSC);
    cx = min(max(cx, 0), GC - 1);
    cy = min(max(cy, 0), GC - 1);
    cz = min(max(cz, 0), GC - 1);
    return (int)((expand5((unsigned)cz) << 2) | (expand5((unsigned)cy) << 1) | expand5((unsigned)cx));
}

// ---------------------------------------------------------------------------
__global__ __launch_bounds__(256) void wcvt_kernel(
    const float* __restrict__ W1, const float* __restrict__ W2,
    _Float16* __restrict__ W1c, _Float16* __restrict__ W2c)
{
    int i = blockIdx.x * 256 + threadIdx.x;
    if (i < C1 * (D1 + D2)) W1c[i] = (_Float16)W1[i];
    if (i < C2 * C1)        W2c[i] = (_Float16)W2[i];
}

// ---------------------------------------------------------------------------
// Morton histogram (candidates + queries, one launch).
// ---------------------------------------------------------------------------
__global__ __launch_bounds__(256) void histo_kernel(
    const float* __restrict__ xyz2, const float* __restrict__ xyz1,
    unsigned* __restrict__ histC, unsigned* __restrict__ histQ)
{
    int i = blockIdx.x * 256 + threadIdx.x;
    if (i < BB * SS) {
        int b = i >> 12;
        float x = xyz2[(size_t)i*3+0], y = xyz2[(size_t)i*3+1], z = xyz2[(size_t)i*3+2];
        atomicAdd(&histC[(size_t)b * NCELL + morton_of(x, y, z)], 1u);
    } else {
        int j = i - BB * SS;
        int b = j >> 14;
        float x = xyz1[(size_t)j*3+0], y = xyz1[(size_t)j*3+1], z = xyz1[(size_t)j*3+2];
        atomicAdd(&histQ[(size_t)b * NCELL + morton_of(x, y, z)], 1u);
    }
}

// blocks 0..3: candidate hist -> startC + nextC ; 4..7: query hist -> nextQ
__global__ __launch_bounds__(256) void scan_kernel(
    const unsigned* __restrict__ histC, unsigned* __restrict__ startC,
    unsigned* __restrict__ nextC,
    const unsigned* __restrict__ histQ, unsigned* __restrict__ nextQ)
{
    __shared__ unsigned ps[256];
    const int blk = blockIdx.x;
    const bool isC = blk < 4;
    const int b = isC ? blk : blk - 4;
    const unsigned* h = (isC ? histC : histQ) + (size_t)b * NCELL;
    unsigned* st = isC ? startC + (size_t)b * NCELL : nullptr;
    unsigned* nx = (isC ? nextC : nextQ) + (size_t)b * NCELL;
    const int tid = threadIdx.x;
    const int PB = NCELL / 256;        // 128
    unsigned loc = 0;
    for (int i = 0; i < PB; ++i) loc += h[tid * PB + i];
    ps[tid] = loc;
    __syncthreads();
#pragma unroll
    for (int d = 1; d < 256; d <<= 1) {
        unsigned v = (tid >= d) ? ps[tid - d] : 0u;
        __syncthreads();
        ps[tid] += v;
        __syncthreads();
    }
    unsigned run = ps[tid] - loc;      // exclusive prefix
    for (int i = 0; i < PB; ++i) {
        unsigned c = h[tid * PB + i];
        if (st) st[tid * PB + i] = run;
        nx[tid * PB + i] = run;
        run += c;
    }
}

// Scatter: candidates -> {-2x,-2y,-2z,||p||^2} (exact pow2 scaling -> the d
// formula stays BIT-EXACT vs reference) + original index; queries -> qperm.
__global__ __launch_bounds__(256) void scatter_kernel(
    const float* __restrict__ xyz2, const float* __restrict__ xyz1,
    unsigned* __restrict__ nextC, unsigned* __restrict__ nextQ,
    float4* __restrict__ sPk, unsigned short* __restrict__ sIdx,
    int* __restrict__ qperm)
{
#pragma clang fp contract(off)
    int i = blockIdx.x * 256 + threadIdx.x;
    if (i < BB * SS) {
        int b = i >> 12;
        int s = i & (SS - 1);
        float px = xyz2[(size_t)i*3+0], py = xyz2[(size_t)i*3+1], pz = xyz2[(size_t)i*3+2];
        int c = morton_of(px, py, pz);
        unsigned pos = atomicAdd(&nextC[(size_t)b * NCELL + c], 1u);
        float pp = (px*px + py*py) + pz*pz;
        sPk[(size_t)b * SS + pos] = make_float4(-2.0f*px, -2.0f*py, -2.0f*pz, pp);
        sIdx[(size_t)b * SS + pos] = (unsigned short)s;
    } else {
        int j = i - BB * SS;
        int b = j >> 14;
        float x = xyz1[(size_t)j*3+0], y = xyz1[(size_t)j*3+1], z = xyz1[(size_t)j*3+2];
        int c = morton_of(x, y, z);
        unsigned pos = atomicAdd(&nextQ[(size_t)b * NCELL + c], 1u);
        qperm[(size_t)b * NN + pos] = j;  // global query row
    }
}

// Per-chunk AABB (256 Morton-sorted candidates each; exact coords = -0.5*x).
__global__ __launch_bounds__(256) void aabbc_kernel(
    const float4* __restrict__ sPk, float4* __restrict__ aabbC)
{
    __shared__ float red[6][4];
    int cid = blockIdx.x;              // BB*NCH = 64
    int b = cid >> 4, c = cid & (NCH - 1);
    int tid = threadIdx.x;
    float4 p = sPk[(size_t)b * SS + c * SCH + tid];
    float x = -0.5f * p.x, y = -0.5f * p.y, z = -0.5f * p.z;
    float mnx = x, mny = y, mnz = z, mxx = x, mxy = y, mxz = z;
#pragma unroll
    for (int d = 1; d < 64; d <<= 1) {
        mnx = fminf(mnx, __shfl_xor(mnx, d)); mxx = fmaxf(mxx, __shfl_xor(mxx, d));
        mny = fminf(mny, __shfl_xor(mny, d)); mxy = fmaxf(mxy, __shfl_xor(mxy, d));
        mnz = fminf(mnz, __shfl_xor(mnz, d)); mxz = fmaxf(mxz, __shfl_xor(mxz, d));
    }
    int wv = tid >> 6, ln = tid & 63;
    if (ln == 0) {
        red[0][wv] = mnx; red[1][wv] = mny; red[2][wv] = mnz;
        red[3][wv] = mxx; red[4][wv] = mxy; red[5][wv] = mxz;
    }
    __syncthreads();
    if (tid == 0) {
        float a0 = fminf(fminf(red[0][0], red[0][1]), fminf(red[0][2], red[0][3]));
        float a1 = fminf(fminf(red[1][0], red[1][1]), fminf(red[1][2], red[1][3]));
        float a2 = fminf(fminf(red[2][0], red[2][1]), fminf(red[2][2], red[2][3]));
        float a3 = fmaxf(fmaxf(red[3][0], red[3][1]), fmaxf(red[3][2], red[3][3]));
        float a4 = fmaxf(fmaxf(red[4][0], red[4][1]), fmaxf(red[4][2], red[4][3]));
        float a5 = fmaxf(fmaxf(red[5][0], red[5][1]), fmaxf(red[5][2], red[5][3]));
        aabbC[(size_t)cid * 2 + 0] = make_float4(a0, a1, a2, 0.0f);
        aabbC[(size_t)cid * 2 + 1] = make_float4(a3, a4, a5, 0.0f);
    }
}

// ---------------------------------------------------------------------------
// Phase A: per-query upper bound ub = 3rd-smallest exact d over one
// block-uniform seed chunk (ANY subset's 3rd-NN distance is a valid upper
// bound -> conservative). d formula identical to the verified one.
// ---------------------------------------------------------------------------
__global__ void ub_kernel(
    const float* __restrict__ xyz1, const float4* __restrict__ sPk,
    const unsigned* __restrict__ startC, const int* __restrict__ qperm,
    float* __restrict__ ub)
{
#pragma clang fp contract(off)
    __shared__ float4 pk[SCH];
    __shared__ int chs_s;
    const int tid = threadIdx.x;
    const int b = blockIdx.x >> 6;                 // NN/256 = 64 blocks/batch
    const int n0 = (blockIdx.x & 63) * 256;
    if (tid == 0) {
        int q0 = qperm[(size_t)b * NN + n0];
        float x = xyz1[(size_t)q0*3+0], y = xyz1[(size_t)q0*3+1], z = xyz1[(size_t)q0*3+2];
        chs_s = min((int)(startC[(size_t)b * NCELL + morton_of(x, y, z)] >> 8), NCH - 1);
    }
    __syncthreads();
    const int ch = chs_s;
    pk[tid] = sPk[(size_t)b * SS + ch * SCH + tid];
    __syncthreads();

    const int qid = qperm[(size_t)b * NN + n0 + tid];
    const float qx = xyz1[(size_t)qid*3+0];
    const float qy = xyz1[(size_t)qid*3+1];
    const float qz = xyz1[(size_t)qid*3+2];
    const float qq = (qx*qx + qy*qy) + qz*qz;
    float e0 = 3.4e38f, e1 = 3.4e38f, e2 = 3.4e38f;

    for (int s = 0; s < SCH; s += 4) {
        float4 P0 = pk[s+0], P1 = pk[s+1], P2v = pk[s+2], P3 = pk[s+3];
#pragma unroll
        for (int t = 0; t < 4; ++t) {
            float4 p = (t == 0) ? P0 : (t == 1) ? P1 : (t == 2) ? P2v : P3;
            float cr2 = (qx*p.x + qy*p.y) + qz*p.z;
            float d = (qq + cr2) + p.w;
            d = fmaxf(d, 0.0f);
            e2 = __builtin_amdgcn_fmed3f(e1, d, e2);
            e1 = __builtin_amdgcn_fmed3f(e0, d, e1);
            e0 = fminf(e0, d);
        }
    }
    ub[(size_t)b * NN + n0 + tid] = e2;
}

// ---------------------------------------------------------------------------
// Phase B: R3 partial engine over Morton-sorted queries/candidates with
// per-wave conservative chunk skip (bnd >= ub+SLACK for all 128 wave queries
// -> sentinels). Lex-(d,s) insertion == lax.top_k stable order (validated
// R5/R6). HARD CONSTRAINT (R7): distance formula and comparison are exact;
// the skip test can never drop a true top-3 member (SLACK >> fp rounding,
// ub is a true upper bound, and each query's Phase-A chunk always survives).
// ---------------------------------------------------------------------------
__global__ __launch_bounds__(256, 6) void knn3_partial_kernel(
    const float* __restrict__ xyz1, const float4* __restrict__ sPk,
    const unsigned short* __restrict__ sIdx, const int* __restrict__ qperm,
    const float* __restrict__ ub, const float4* __restrict__ aabbC,
    float* __restrict__ pd0, float* __restrict__ pd1, float* __restrict__ pd2,
    int* __restrict__ pi0, int* __restrict__ pi1, int* __restrict__ pi2)
{
#pragma clang fp contract(off)
    __shared__ float4 pk[SCH];                     // 4 KB
    __shared__ unsigned short sid[SCH];            // 512 B

    const int qblocks = NN / (256 * QPT);          // 32
    const int b  = blockIdx.x / (qblocks * NCH);
    const int r  = blockIdx.x % (qblocks * NCH);
    const int qc = r / NCH;
    const int sc = r % NCH;
    const int tid = threadIdx.x;

    pk[tid]  = sPk [(size_t)b * SS + sc * SCH + tid];
    sid[tid] = sIdx[(size_t)b * SS + sc * SCH + tid];
    __syncthreads();

    float qx[QPT], qy[QPT], qz[QPT], qq[QPT], ubq[QPT];
    int n_[QPT];
#pragma unroll
    for (int q = 0; q < QPT; ++q) {
        int n = qc * (256 * QPT) + q * 256 + tid;
        n_[q] = n;
        int qid = qperm[(size_t)b * NN + n];
        qx[q] = xyz1[(size_t)qid*3+0];
        qy[q] = xyz1[(size_t)qid*3+1];
        qz[q] = xyz1[(size_t)qid*3+2];
        qq[q] = (qx[q]*qx[q] + qy[q]*qy[q]) + qz[q]*qz[q];
        ubq[q] = ub[(size_t)b * NN + n];
    }

    // per-wave conservative chunk test
    float4 mn = aabbC[((size_t)b * NCH + sc) * 2 + 0];
    float4 mx = aabbC[((size_t)b * NCH + sc) * 2 + 1];
    bool need = false;
#pragma unroll
    for (int q = 0; q < QPT; ++q) {
        float dx = fmaxf(fmaxf(mn.x - qx[q], qx[q] - mx.x), 0.0f);
        float dy = fmaxf(fmaxf(mn.y - qy[q], qy[q] - mx.y), 0.0f);
        float dz = fmaxf(fmaxf(mn.z - qz[q], qz[q] - mx.z), 0.0f);
        float bnd = (dx*dx + dy*dy) + dz*dz;
        need = need || (bnd < ubq[q] + SLACK);
    }
    if (!__any(need)) {
#pragma unroll
        for (int q = 0; q < QPT; ++q) {
            size_t o = (size_t)sc * MTOT + (size_t)b * NN + n_[q];
            pd0[o] = 3.4e38f; pd1[o] = 3.4e38f; pd2[o] = 3.4e38f;
            pi0[o] = SENT_J;  pi1[o] = SENT_J;  pi2[o] = SENT_J;
        }
        return;
    }

    float e0[QPT], e1[QPT], e2[QPT];
    int   j0[QPT], j1[QPT], j2[QPT];
#pragma unroll
    for (int q = 0; q < QPT; ++q) {
        e0[q] = 3.4e38f; e1[q] = 3.4e38f; e2[q] = 3.4e38f;
        j0[q] = SENT_J;  j1[q] = SENT_J;  j2[q] = SENT_J;
    }

#pragma unroll 4
    for (int s = 0; s < SCH; ++s) {
        float4 p = pk[s];
        int   sI = (int)sid[s];
#pragma unroll
        for (int q = 0; q < QPT; ++q) {
            float cr2 = (qx[q]*p.x + qy[q]*p.y) + qz[q]*p.z;   // == -2*cr exactly
            float d = (qq[q] + cr2) + p.w;
            d = fmaxf(d, 0.0f);
            bool c0 = (d < e0[q]) || (d == e0[q] && sI < j0[q]);
            bool c1 = (d < e1[q]) || (d == e1[q] && sI < j1[q]);
            bool c2 = (d < e2[q]) || (d == e2[q] && sI < j2[q]);
            j2[q] = c1 ? j1[q] : (c2 ? sI : j2[q]);
            e2[q] = c1 ? e1[q] : (c2 ? d  : e2[q]);
            j1[q] = c0 ? j0[q] : (c1 ? sI : j1[q]);
            e1[q] = c0 ? e0[q] : (c1 ? d  : e1[q]);
            j0[q] = c0 ? sI : j0[q];
            e0[q] = c0 ? d  : e0[q];
        }
    }

#pragma unroll
    for (int q = 0; q < QPT; ++q) {
        size_t o = (size_t)sc * MTOT + (size_t)b * NN + n_[q];
        pd0[o] = e0[q]; pd1[o] = e1[q]; pd2[o] = e2[q];
        pi0[o] = j0[q]; pi1[o] = j1[q]; pi2[o] = j2[q];
    }
}

// ---------------------------------------------------------------------------
// Merge: lex-(d,s) over chunks ascending (order-independent given lex).
// Writes final idx/w at the ORIGINAL query row via qperm.
// ---------------------------------------------------------------------------
__global__ __launch_bounds__(256) void knn3_merge_kernel(
    const float* __restrict__ pd0, const float* __restrict__ pd1, const float* __restrict__ pd2,
    const int* __restrict__ pi0, const int* __restrict__ pi1, const int* __restrict__ pi2,
    const int* __restrict__ qperm,
    int* __restrict__ idx_out, float* __restrict__ w_out)
{
#pragma clang fp contract(off)
    int m = blockIdx.x * 256 + threadIdx.x;        // sorted position
    int b = m / NN;

    float d0 = pd0[m], d1 = pd1[m], d2 = pd2[m];
    int   i0 = pi0[m], i1 = pi1[m], i2 = pi2[m];

#pragma unroll
    for (int c = 1; c < NCH; ++c) {
        size_t oc = (size_t)c * MTOT + m;
        float dv[3]; int sv[3];
        dv[0] = pd0[oc]; dv[1] = pd1[oc]; dv[2] = pd2[oc];
        sv[0] = pi0[oc]; sv[1] = pi1[oc]; sv[2] = pi2[oc];
#pragma unroll
        for (int j = 0; j < 3; ++j) {
            float d = dv[j]; int s = sv[j];
            bool c0 = (d < d0) || (d == d0 && s < i0);
            bool c1 = (d < d1) || (d == d1 && s < i1);
            bool c2 = (d < d2) || (d == d2 && s < i2);
            d2 = c1 ? d1 : (c2 ? d : d2);  i2 = c1 ? i1 : (c2 ? s : i2);
            d1 = c0 ? d0 : (c1 ? d : d1);  i1 = c0 ? i0 : (c1 ? s : i1);
            d0 = c0 ? d : d0;              i0 = c0 ? s : i0;
        }
    }
    float r0 = 1.0f / (d0 + 1e-8f);
    float r1 = 1.0f / (d1 + 1e-8f);
    float r2 = 1.0f / (d2 + 1e-8f);
    float inv = 1.0f / ((r0 + r1) + r2);
    int qid = qperm[m];
    idx_out[(size_t)qid*3+0] = b * SS + i0;
    idx_out[(size_t)qid*3+1] = b * SS + i1;
    idx_out[(size_t)qid*3+2] = b * SS + i2;
    w_out[(size_t)qid*3+0] = r0 * inv;
    w_out[(size_t)qid*3+1] = r1 * inv;
    w_out[(size_t)qid*3+2] = r2 * inv;
}

// ---------------------------------------------------------------------------
// fp16 MFMA GEMM, LDS double-buffered with ONE barrier per k-iter.
// ---------------------------------------------------------------------------
template<int K, typename AT, typename OT, bool BN_A, bool FUSE_STATS>
__global__ __launch_bounds__(256, 4) void gemm_mfma_kernel(
    const AT* __restrict__ A, int lda,
    const _Float16* __restrict__ W, int ldw,
    OT* __restrict__ C, int ldc,
    const float* __restrict__ bias,
    const float* __restrict__ scaleA, const float* __restrict__ shiftA,
    float* __restrict__ sumO, float* __restrict__ sqO)
{
    __shared__ _Float16 Ash[2][64 * LPAD];     // 2 x 5 KB
    __shared__ _Float16 Bsh[2][128 * LPAD];    // 2 x 10 KB

    const int tid = threadIdx.x;
    const int m0 = blockIdx.x * 64;
    const int n0 = blockIdx.y * 128;
    const int wave = tid >> 6, lane = tid & 63;
    const int ln = lane & 15, q4 = lane >> 4;
    const int wm = wave & 1, wn = wave >> 1;

    const int ar = tid >> 2, ak = (tid & 3) * 8;
    const int br = tid >> 1, bk = (tid & 1) * 16;

    f32x4 acc[2][4] = {};

    float  avF[8];
    f16x8  avH;
    f16x8  bvA[2];

    {   // prologue prefetch k0 = 0
        if constexpr (__is_same(AT, float)) {
            const float* ap = A + (size_t)(m0 + ar) * lda + ak;
            *(float4*)&avF[0] = *(const float4*)ap;
            *(float4*)&avF[4] = *(const float4*)(ap + 4);
        } else {
            avH = *(const f16x8*)(A + (size_t)(m0 + ar) * lda + ak);
        }
        const _Float16* bp = W + (size_t)(n0 + br) * ldw + bk;
        bvA[0] = *(const f16x8*)bp;
        bvA[1] = *(const f16x8*)(bp + 8);
    }

    for (int k0 = 0; k0 < K; k0 += 32) {
        const int buf = (k0 >> 5) & 1;

        {
            float av[8];
            if constexpr (__is_same(AT, float)) {
#pragma unroll
                for (int i = 0; i < 8; ++i) av[i] = avF[i];
            } else {
#pragma unroll
                for (int i = 0; i < 8; ++i) av[i] = (float)avH[i];
            }
            if (BN_A) {
#pragma unroll
                for (int i = 0; i < 8; ++i) {
                    float sc = scaleA[k0 + ak + i];
                    float sh = shiftA[k0 + ak + i];
                    av[i] = fmaxf(av[i] * sc + sh, 0.0f);
                }
            }
            f16x8 vh;
#pragma unroll
            for (int i = 0; i < 8; ++i) vh[i] = (_Float16)av[i];
            *(f16x8*)&Ash[buf][ar * LPAD + ak] = vh;
            *(f16x8*)&Bsh[buf][br * LPAD + bk]     = bvA[0];
            *(f16x8*)&Bsh[buf][br * LPAD + bk + 8] = bvA[1];
        }
        __syncthreads();

        if (k0 + 32 < K) {
            if constexpr (__is_same(AT, float)) {
                const float* ap = A + (size_t)(m0 + ar) * lda + (k0 + 32) + ak;
                *(float4*)&avF[0] = *(const float4*)ap;
                *(float4*)&avF[4] = *(const float4*)(ap + 4);
            } else {
                avH = *(const f16x8*)(A + (size_t)(m0 + ar) * lda + (k0 + 32) + ak);
            }
            const _Float16* bp = W + (size_t)(n0 + br) * ldw + (k0 + 32) + bk;
            bvA[0] = *(const f16x8*)bp;
            bvA[1] = *(const f16x8*)(bp + 8);
        }

        f16x8 af[2];
#pragma unroll
        for (int mi = 0; mi < 2; ++mi) {
            int arow = wm * 32 + mi * 16 + ln;
            af[mi] = *(const f16x8*)&Ash[buf][arow * LPAD + q4 * 8];
        }
        f16x8 bf[4];
#pragma unroll
        for (int ni = 0; ni < 4; ++ni) {
            int brow = wn * 64 + ni * 16 + ln;
            bf[ni] = *(const f16x8*)&Bsh[buf][brow * LPAD + q4 * 8];
        }
#pragma unroll
        for (int mi = 0; mi < 2; ++mi)
#pragma unroll
            for (int ni = 0; ni < 4; ++ni)
                acc[mi][ni] = __builtin_amdgcn_mfma_f32_16x16x32_f16(af[mi], bf[ni], acc[mi][ni], 0, 0, 0);
    }

#pragma unroll
    for (int ni = 0; ni < 4; ++ni) {
        int col = n0 + wn * 64 + ni * 16 + ln;
        float vb = bias ? bias[col] : 0.0f;
        float s = 0.0f, s2 = 0.0f;
#pragma unroll
        for (int mi = 0; mi < 2; ++mi) {
#pragma unroll
            for (int r = 0; r < 4; ++r) {
                int row_g = m0 + wm * 32 + mi * 16 + q4 * 4 + r;
                float v = acc[mi][ni][r] + vb;
                C[(size_t)row_g * ldc + col] = (OT)v;
                s += v; s2 += v * v;
            }
        }
        if (FUSE_STATS) {
            s  += __shfl_xor(s, 16);  s  += __shfl_xor(s, 32);
            s2 += __shfl_xor(s2, 16); s2 += __shfl_xor(s2, 32);
            if (q4 == 0) {
                atomicAdd(&sumO[col], s);
                atomicAdd(&sqO[col], s2);
            }
        }
    }
}

// ---------------------------------------------------------------------------
// Dedicated interp + bias + BN1-stats kernel.
// ---------------------------------------------------------------------------
__global__ __launch_bounds__(256, 8) void interp_stats_kernel(
    const float* __restrict__ temp,
    const _Float16* __restrict__ P2,
    const int* __restrict__ idx3, const float* __restrict__ w3,
    const float* __restrict__ bias,
    _Float16* __restrict__ Y,
    float* __restrict__ sumO, float* __restrict__ sqO)
{
    __shared__ float sred[2 * C1];
    const int tid = threadIdx.x;
    const int sl  = tid & 31;
    const int rg  = tid >> 5;
    const int m0  = blockIdx.x * 32;

    sred[tid] = 0.0f; sred[tid + 256] = 0.0f;
    __syncthreads();

    float bv[8];
    *(float4*)&bv[0] = *(const float4*)(bias + sl * 8);
    *(float4*)&bv[4] = *(const float4*)(bias + sl * 8 + 4);

    float sAcc[8]  = {0.f,0.f,0.f,0.f,0.f,0.f,0.f,0.f};
    float s2Acc[8] = {0.f,0.f,0.f,0.f,0.f,0.f,0.f,0.f};

#pragma unroll
    for (int rr = 0; rr < 4; ++rr) {
        const int row = m0 + rg * 4 + rr;
        const int*   ip = idx3 + (size_t)row * 3;
        const float* wp = w3   + (size_t)row * 3;
        int   ia = ip[0], ib = ip[1], ic = ip[2];
        float wa = wp[0], wb = wp[1], wc = wp[2];

        float av[8];
        const float* tp = temp + (size_t)row * C1 + sl * 8;
        *(float4*)&av[0] = *(const float4*)tp;
        *(float4*)&av[4] = *(const float4*)(tp + 4);
        f16x8 pa = *(const f16x8*)(P2 + (size_t)ia * C1 + sl * 8);
        f16x8 pb = *(const f16x8*)(P2 + (size_t)ib * C1 + sl * 8);
        f16x8 pc = *(const f16x8*)(P2 + (size_t)ic * C1 + sl * 8);

        f16x8 outv;
#pragma unroll
        for (int i = 0; i < 8; ++i) {
            float v = av[i];
            v += wa * (float)pa[i];
            v += wb * (float)pb[i];
            v += wc * (float)pc[i];
            v += bv[i];
            outv[i] = (_Float16)v;
            sAcc[i]  += v;
            s2Acc[i] += v * v;
        }
        *(f16x8*)(Y + (size_t)row * C1 + sl * 8) = outv;
    }

#pragma unroll
    for (int i = 0; i < 8; ++i) {
        atomicAdd(&sred[sl * 8 + i],       sAcc[i]);
        atomicAdd(&sred[256 + sl * 8 + i], s2Acc[i]);
    }
    __syncthreads();
    atomicAdd(&sumO[tid], sred[tid]);
    atomicAdd(&sqO[tid],  sred[tid + 256]);
}

// ---------------------------------------------------------------------------
__global__ void finalize_kernel(
    const float* __restrict__ sum, const float* __restrict__ sumsq,
    const float* __restrict__ g, const float* __restrict__ beta,
    int M, int C, float* __restrict__ scale, float* __restrict__ shift)
{
    int c = threadIdx.x;
    if (c >= C) return;
    float invM = 1.0f / (float)M;
    float mean = sum[c] * invM;
    float var = fmaxf(sumsq[c] * invM - mean * mean, 0.0f);
    float rstd = 1.0f / sqrtf(var + 1e-5f);
    float sc = g[c] * rstd;
    scale[c] = sc;
    shift[c] = beta[c] - mean * sc;
}

__global__ __launch_bounds__(256) void bnrelu_kernel(
    float* __restrict__ X, int total4, int C,
    const float* __restrict__ scale, const float* __restrict__ shift)
{
    int i = blockIdx.x * 256 + threadIdx.x;
    if (i >= total4) return;
    float4 v = ((const float4*)X)[i];
    int c = (i * 4) & (C - 1);
    v.x = fmaxf(v.x * scale[c+0] + shift[c+0], 0.0f);
    v.y = fmaxf(v.y * scale[c+1] + shift[c+1], 0.0f);
    v.z = fmaxf(v.z * scale[c+2] + shift[c+2], 0.0f);
    v.w = fmaxf(v.w * scale[c+3] + shift[c+3], 0.0f);
    ((float4*)X)[i] = v;
}

// ---------------------------------------------------------------------------
extern "C" void kernel_launch(void* const* d_in, const int* in_sizes, int n_in,
                              void* d_out, int out_size, void* d_ws, size_t ws_size,
                              hipStream_t stream) {
    const float* xyz1    = (const float*)d_in[0];
    const float* xyz2    = (const float*)d_in[1];
    const float* points1 = (const float*)d_in[2];
    const float* points2 = (const float*)d_in[3];
    const float* W1      = (const float*)d_in[4];
    const float* b1      = (const float*)d_in[5];
    const float* g1      = (const float*)d_in[6];
    const float* beta1   = (const float*)d_in[7];
    const float* W2      = (const float*)d_in[8];
    const float* b2      = (const float*)d_in[9];
    const float* g2      = (const float*)d_in[10];
    const float* beta2   = (const float*)d_in[11];
    float* out = (float*)d_out;

    // ws layout
    char* ws = (char*)d_ws;
    size_t off = 0;
    int*   idx = (int*)(ws + off);            off += (size_t)MTOT*3*4;
    float* w   = (float*)(ws + off);          off += (size_t)MTOT*3*4;
    _Float16* P2h = (_Float16*)(ws + off);    off += (size_t)BB*SS*C1*2;    // 8 MB
    _Float16* y1h = (_Float16*)(ws + off);    off += (size_t)MTOT*C1*2;     // 32 MB
    float* stats = (float*)(ws + off);        off += 2048*4;
    float* sum1 = stats;            // 256
    float* sq1  = stats + 256;      // 256
    float* sum2 = stats + 512;      // 128
    float* sq2  = stats + 640;      // 128
    float* scale1 = stats + 768;    // 256
    float* shift1 = stats + 1024;   // 256
    float* scale2 = stats + 1280;   // 128
    float* shift2 = stats + 1408;   // 128
    _Float16* W1c = (_Float16*)(ws + off);    off += (size_t)C1*(D1+D2)*2;
    _Float16* W2c = (_Float16*)(ws + off);    off += (size_t)C2*C1*2;
    off = (off + 255) & ~(size_t)255;
    float* tempf = (float*)(ws + off);        off += (size_t)MTOT*C1*4;     // 64 MB

    // knn arrays alias the y1h region (32 MB; y1h written later by interp).
    char* al = (char*)y1h;
    size_t ao = 0;
    float4* sPk = (float4*)(al + ao);                 ao += (size_t)BB*SS*16;       // 256 KB
    unsigned short* sIdx = (unsigned short*)(al+ao);  ao += (size_t)BB*SS*2;        // 32 KB
    int* qperm = (int*)(al + ao);                     ao += (size_t)BB*NN*4;        // 256 KB
    unsigned* histC = (unsigned*)(al + ao);           ao += (size_t)BB*NCELL*4;     // 512 KB
    unsigned* histQ = (unsigned*)(al + ao);           ao += (size_t)BB*NCELL*4;     // 512 KB
    unsigned* startC = (unsigned*)(al + ao);          ao += (size_t)BB*NCELL*4;     // 512 KB
    unsigned* nextC = (unsigned*)(al + ao);           ao += (size_t)BB*NCELL*4;     // 512 KB
    unsigned* nextQ = (unsigned*)(al + ao);           ao += (size_t)BB*NCELL*4;     // 512 KB
    float4* aabbC = (float4*)(al + ao);               ao += (size_t)BB*NCH*2*16;    // 2 KB
    float* ubA = (float*)(al + ao);                   ao += (size_t)MTOT*4;         // 256 KB
    ao = (ao + 255) & ~(size_t)255;
    float* pd0 = (float*)(al + ao);                   // 6 planes x NCH*MTOT*4 = 25.2 MB
    float* pd1 = pd0 + (size_t)NCH*MTOT;
    float* pd2 = pd1 + (size_t)NCH*MTOT;
    int*   pi0 = (int*)(pd2 + (size_t)NCH*MTOT);
    int*   pi1 = pi0 + (size_t)NCH*MTOT;
    int*   pi2 = pi1 + (size_t)NCH*MTOT;

    hipMemsetAsync(stats, 0, 768 * sizeof(float), stream);
    hipMemsetAsync(histC, 0, (size_t)BB * NCELL * 4 * 2, stream);  // histC + histQ

    wcvt_kernel<<<(C1*(D1+D2))/256, 256, 0, stream>>>(W1, W2, W1c, W2c);

    // ---- Morton sort pipeline ----
    histo_kernel<<<(BB*(SS+NN))/256, 256, 0, stream>>>(xyz2, xyz1, histC, histQ);
    scan_kernel<<<8, 256, 0, stream>>>(histC, startC, nextC, histQ, nextQ);
    scatter_kernel<<<(BB*(SS+NN))/256, 256, 0, stream>>>(
        xyz2, xyz1, nextC, nextQ, sPk, sIdx, qperm);
    aabbc_kernel<<<BB*NCH, 256, 0, stream>>>(sPk, aabbC);

    // ---- Phase A: per-query upper bound ----
    ub_kernel<<<MTOT/256, 256, 0, stream>>>(xyz1, sPk, startC, qperm, ubA);

    // ---- Phase B: pruned partial scans + merge ----
    knn3_partial_kernel<<<BB * (NN/(256*QPT)) * NCH, 256, 0, stream>>>(
        xyz1, sPk, sIdx, qperm, ubA, aabbC, pd0, pd1, pd2, pi0, pi1, pi2);
    knn3_merge_kernel<<<MTOT/256, 256, 0, stream>>>(
        pd0, pd1, pd2, pi0, pi1, pi2, qperm, idx, w);

    // P2 = points2 @ W1[:,128:]^T   [B*S x 256], K=256, f16 out
    gemm_mfma_kernel<256, float, _Float16, false, false>
        <<<dim3((BB*SS)/64, C1/128), 256, 0, stream>>>(
        points2, D2, W1c + D1, D1 + D2, P2h, C1,
        nullptr, nullptr, nullptr, nullptr, nullptr);

    // temp = points1 @ W1[:,:128]^T   (plain GEMM, fp32 out)
    gemm_mfma_kernel<128, float, float, false, false>
        <<<dim3(MTOT/64, C1/128), 256, 0, stream>>>(
        points1, D1, W1c, D1 + D2, tempf, C1,
        nullptr, nullptr, nullptr, nullptr, nullptr);

    // y1 = temp + interp(P2) + b1  (f16 out) + BN1 stats
    interp_stats_kernel<<<MTOT/32, 256, 0, stream>>>(
        tempf, P2h, idx, w, b1, y1h, sum1, sq1);

    finalize_kernel<<<1, 256, 0, stream>>>(sum1, sq1, g1, beta1, MTOT, C1, scale1, shift1);

    // out = relu(bn1(y1)) @ W2^T + b2;  fp32 out; fused BN2 stats
    gemm_mfma_kernel<256, _Float16, float, true, true>
        <<<dim3(MTOT/64, C2/128), 256, 0, stream>>>(
        y1h, C1, W2c, C1, out, C2,
        b2, scale1, shift1, sum2, sq2);

    finalize_kernel<<<1, 128, 0, stream>>>(sum2, sq2, g2, beta2, MTOT, C2, scale2, shift2);
    bnrelu_kernel<<<(MTOT*C2/4)/256, 256, 0, stream>>>(out, MTOT*C2/4, C2, scale2, shift2);
}

// Round 9
// 344.396 us; speedup vs baseline: 2.1254x; 1.5482x over previous
//
#include <hip/hip_runtime.h>
#include <hip/hip_bf16.h>
#include <math.h>

// Problem constants (fixed by setup_inputs)
#define BB 4
#define NN 16384
#define SS 4096
#define D1 128
#define D2 256
#define C1 256   // mlp[0]
#define C2 128   // mlp[1]
#define MTOT (BB*NN)   // 65536

// knn decomposition (R8: NCH=16; R15: 128-thread blocks -> 4096 blocks =
// 16 blocks/CU = 32 waves/CU occupancy cap; R4 measured 56% occ at 2048x256)
#define QPT 2              // queries per thread
#define SCH 256            // candidates per chunk (4KB LDS)
#define NCH (SS/SCH)       // 16 chunks
#define PTH 128            // threads per partial block

typedef _Float16 f16x8 __attribute__((ext_vector_type(8)));
typedef float f32x4  __attribute__((ext_vector_type(4)));
typedef int   i32x4  __attribute__((ext_vector_type(4)));

#define LPAD 40            // LDS row stride in fp16 elems (80B, 16B-aligned)

// ---------------------------------------------------------------------------
// Pack xyz2 into float4 {-2x, -2y, -2z, ||p||^2} (bit-exact vs reference:
// x(-2) is exact pow2 scaling, so (qq + cr2) + pw == (qq - 2*cr) + pw).
// ---------------------------------------------------------------------------
__global__ __launch_bounds__(256) void pack_kernel(
    const float* __restrict__ xyz2, float4* __restrict__ packed)
{
#pragma clang fp contract(off)
    int s = blockIdx.x * 256 + threadIdx.x;
    float px = xyz2[s*3+0], py = xyz2[s*3+1], pz = xyz2[s*3+2];
    float pp = (px*px + py*py) + pz*pz;
    packed[s] = make_float4(-2.0f*px, -2.0f*py, -2.0f*pz, pp);
}

// ---------------------------------------------------------------------------
// Convert W1, W2 to fp16 (RNE) once.
// ---------------------------------------------------------------------------
__global__ __launch_bounds__(256) void wcvt_kernel(
    const float* __restrict__ W1, const float* __restrict__ W2,
    _Float16* __restrict__ W1c, _Float16* __restrict__ W2c)
{
    int i = blockIdx.x * 256 + threadIdx.x;
    if (i < C1 * (D1 + D2)) W1c[i] = (_Float16)W1[i];
    if (i < C2 * C1)        W2c[i] = (_Float16)W2[i];
}

// ---------------------------------------------------------------------------
// 3-NN pass 1 (R4 engine, proven 153us @56% occ; R15 = 128-thr blocks for
// occupancy): exact fp32 distances (contract off), min/med3 distance chain +
// cndmask index chain, strict '<' with ascending candidate order (stable,
// == lax.top_k). HARD CONSTRAINT (R7): selection is discontinuous in the
// gathered features -> never approximate the distance or the comparison.
// ---------------------------------------------------------------------------
__global__ __launch_bounds__(PTH, 8) void knn3_partial_kernel(
    const float* __restrict__ xyz1, const float4* __restrict__ packed,
    float* __restrict__ pd0, float* __restrict__ pd1, float* __restrict__ pd2,
    int* __restrict__ pi0, int* __restrict__ pi1, int* __restrict__ pi2)
{
#pragma clang fp contract(off)
    __shared__ float4 pk[SCH];                       // 4 KB

    const int qblocks = NN / (PTH * QPT);            // 64
    const int b  = blockIdx.x / (qblocks * NCH);
    const int r  = blockIdx.x % (qblocks * NCH);
    const int qc = r / NCH;
    const int sc = r % NCH;

    const float4* src = packed + (size_t)b * SS + sc * SCH;
    for (int i = threadIdx.x; i < SCH; i += PTH) pk[i] = src[i];
    __syncthreads();

    float qx[QPT], qy[QPT], qz[QPT], qq[QPT];
    float e0[QPT], e1[QPT], e2[QPT];
    int   j0[QPT], j1[QPT], j2[QPT];
#pragma unroll
    for (int q = 0; q < QPT; ++q) {
        int n = qc * (PTH * QPT) + q * PTH + threadIdx.x;
        size_t m = (size_t)b * NN + n;
        qx[q] = xyz1[m*3+0]; qy[q] = xyz1[m*3+1]; qz[q] = xyz1[m*3+2];
        qq[q] = (qx[q]*qx[q] + qy[q]*qy[q]) + qz[q]*qz[q];
        e0[q] = 3.4e38f; e1[q] = 3.4e38f; e2[q] = 3.4e38f;
        j0[q] = 0; j1[q] = 0; j2[q] = 0;
    }

#pragma unroll 4
    for (int s = 0; s < SCH; ++s) {
        float4 p = pk[s];
#pragma unroll
        for (int q = 0; q < QPT; ++q) {
            float cr2 = (qx[q]*p.x + qy[q]*p.y) + qz[q]*p.z;   // == -2*cr exactly
            float d = (qq[q] + cr2) + p.w;
            d = fmaxf(d, 0.0f);
            bool c0 = d < e0[q], c1 = d < e1[q], c2 = d < e2[q];
            j2[q] = c1 ? j1[q] : (c2 ? s : j2[q]);
            j1[q] = c0 ? j0[q] : (c1 ? s : j1[q]);
            j0[q] = c0 ? s : j0[q];
            e2[q] = __builtin_amdgcn_fmed3f(e1[q], d, e2[q]);
            e1[q] = __builtin_amdgcn_fmed3f(e0[q], d, e1[q]);
            e0[q] = fminf(e0[q], d);
        }
    }

#pragma unroll
    for (int q = 0; q < QPT; ++q) {
        int n = qc * (PTH * QPT) + q * PTH + threadIdx.x;
        size_t m = (size_t)b * NN + n;
        size_t o = (size_t)sc * MTOT + m;
        pd0[o] = e0[q]; pd1[o] = e1[q]; pd2[o] = e2[q];
        pi0[o] = sc*SCH + j0[q];
        pi1[o] = sc*SCH + j1[q];
        pi2[o] = sc*SCH + j2[q];
    }
}

// ---------------------------------------------------------------------------
// 3-NN pass 2: merge chunk triples (ascending chunk order, ascending j within
// chunk, strict '<') — identical scan order to a full ascending pass.
// SoA planes -> all loads lane-coalesced and mutually independent.
// ---------------------------------------------------------------------------
__global__ __launch_bounds__(256) void knn3_merge_kernel(
    const float* __restrict__ pd0, const float* __restrict__ pd1, const float* __restrict__ pd2,
    const int* __restrict__ pi0, const int* __restrict__ pi1, const int* __restrict__ pi2,
    int* __restrict__ idx_out, float* __restrict__ w_out)
{
#pragma clang fp contract(off)
    int m = blockIdx.x * 256 + threadIdx.x;
    int b = m / NN;

    float d0 = pd0[m], d1 = pd1[m], d2 = pd2[m];
    int   i0 = pi0[m], i1 = pi1[m], i2 = pi2[m];

#pragma unroll
    for (int c = 1; c < NCH; ++c) {
        size_t oc = (size_t)c * MTOT + m;
        float da = pd0[oc], db = pd1[oc], dc = pd2[oc];
        int   sa = pi0[oc], sb = pi1[oc], scv = pi2[oc];
        {
            float d = da; int s = sa;
            bool c0 = d < d0, c1 = d < d1, c2 = d < d2;
            d2 = c1 ? d1 : (c2 ? d : d2);  i2 = c1 ? i1 : (c2 ? s : i2);
            d1 = c0 ? d0 : (c1 ? d : d1);  i1 = c0 ? i0 : (c1 ? s : i1);
            d0 = c0 ? d : d0;              i0 = c0 ? s : i0;
        }
        {
            float d = db; int s = sb;
            bool c0 = d < d0, c1 = d < d1, c2 = d < d2;
            d2 = c1 ? d1 : (c2 ? d : d2);  i2 = c1 ? i1 : (c2 ? s : i2);
            d1 = c0 ? d0 : (c1 ? d : d1);  i1 = c0 ? i0 : (c1 ? s : i1);
            d0 = c0 ? d : d0;              i0 = c0 ? s : i0;
        }
        {
            float d = dc; int s = scv;
            bool c0 = d < d0, c1 = d < d1, c2 = d < d2;
            d2 = c1 ? d1 : (c2 ? d : d2);  i2 = c1 ? i1 : (c2 ? s : i2);
            d1 = c0 ? d0 : (c1 ? d : d1);  i1 = c0 ? i0 : (c1 ? s : i1);
            d0 = c0 ? d : d0;              i0 = c0 ? s : i0;
        }
    }
    float r0 = 1.0f / (d0 + 1e-8f);
    float r1 = 1.0f / (d1 + 1e-8f);
    float r2 = 1.0f / (d2 + 1e-8f);
    float inv = 1.0f / ((r0 + r1) + r2);
    idx_out[m*3+0] = b * SS + i0;
    idx_out[m*3+1] = b * SS + i1;
    idx_out[m*3+2] = b * SS + i2;
    w_out[m*3+0] = r0 * inv;
    w_out[m*3+1] = r1 * inv;
    w_out[m*3+2] = r2 * inv;
}

// ---------------------------------------------------------------------------
// fp16 MFMA GEMM, LDS double-buffered with ONE barrier per k-iter.
// C[M x N] = op(A[M x K]) @ W[N x K]^T (+ bias).
// Tile 64(M) x 128(N), 4 waves of 32x64, k-chunk 32 (16x16x32 f16 MFMA).
// ---------------------------------------------------------------------------
template<int K, typename AT, typename OT, bool BN_A, bool FUSE_STATS>
__global__ __launch_bounds__(256, 4) void gemm_mfma_kernel(
    const AT* __restrict__ A, int lda,
    const _Float16* __restrict__ W, int ldw,
    OT* __restrict__ C, int ldc,
    const float* __restrict__ bias,
    const float* __restrict__ scaleA, const float* __restrict__ shiftA,
    float* __restrict__ sumO, float* __restrict__ sqO)
{
    __shared__ _Float16 Ash[2][64 * LPAD];     // 2 x 5 KB
    __shared__ _Float16 Bsh[2][128 * LPAD];    // 2 x 10 KB

    const int tid = threadIdx.x;
    const int m0 = blockIdx.x * 64;
    const int n0 = blockIdx.y * 128;
    const int wave = tid >> 6, lane = tid & 63;
    const int ln = lane & 15, q4 = lane >> 4;
    const int wm = wave & 1, wn = wave >> 1;

    const int ar = tid >> 2, ak = (tid & 3) * 8;   // A staging: 64 rows x 32k
    const int br = tid >> 1, bk = (tid & 1) * 16;  // B staging: 128 rows x 32k

    f32x4 acc[2][4] = {};

    float  avF[8];      // used when AT == float
    f16x8  avH;         // used when AT == _Float16
    f16x8  bvA[2];

    {   // prologue prefetch k0 = 0
        if constexpr (__is_same(AT, float)) {
            const float* ap = A + (size_t)(m0 + ar) * lda + ak;
            *(float4*)&avF[0] = *(const float4*)ap;
            *(float4*)&avF[4] = *(const float4*)(ap + 4);
        } else {
            avH = *(const f16x8*)(A + (size_t)(m0 + ar) * lda + ak);
        }
        const _Float16* bp = W + (size_t)(n0 + br) * ldw + bk;
        bvA[0] = *(const f16x8*)bp;
        bvA[1] = *(const f16x8*)(bp + 8);
    }

    for (int k0 = 0; k0 < K; k0 += 32) {
        const int buf = (k0 >> 5) & 1;

        // ---- transform + store staged regs to LDS[buf] ----
        {
            float av[8];
            if constexpr (__is_same(AT, float)) {
#pragma unroll
                for (int i = 0; i < 8; ++i) av[i] = avF[i];
            } else {
#pragma unroll
                for (int i = 0; i < 8; ++i) av[i] = (float)avH[i];
            }
            if (BN_A) {
#pragma unroll
                for (int i = 0; i < 8; ++i) {
                    float sc = scaleA[k0 + ak + i];
                    float sh = shiftA[k0 + ak + i];
                    av[i] = fmaxf(av[i] * sc + sh, 0.0f);
                }
            }
            f16x8 vh;
#pragma unroll
            for (int i = 0; i < 8; ++i) vh[i] = (_Float16)av[i];
            *(f16x8*)&Ash[buf][ar * LPAD + ak] = vh;
            *(f16x8*)&Bsh[buf][br * LPAD + bk]     = bvA[0];
            *(f16x8*)&Bsh[buf][br * LPAD + bk + 8] = bvA[1];
        }
        __syncthreads();    // single barrier: writers of buf done; dbuf makes it safe

        // ---- issue next chunk's global loads (overlap with MFMA below) ----
        if (k0 + 32 < K) {
            if constexpr (__is_same(AT, float)) {
                const float* ap = A + (size_t)(m0 + ar) * lda + (k0 + 32) + ak;
                *(float4*)&avF[0] = *(const float4*)ap;
                *(float4*)&avF[4] = *(const float4*)(ap + 4);
            } else {
                avH = *(const f16x8*)(A + (size_t)(m0 + ar) * lda + (k0 + 32) + ak);
            }
            const _Float16* bp = W + (size_t)(n0 + br) * ldw + (k0 + 32) + bk;
            bvA[0] = *(const f16x8*)bp;
            bvA[1] = *(const f16x8*)(bp + 8);
        }

        // ---- fragments + MFMA ----
        f16x8 af[2];
#pragma unroll
        for (int mi = 0; mi < 2; ++mi) {
            int arow = wm * 32 + mi * 16 + ln;
            af[mi] = *(const f16x8*)&Ash[buf][arow * LPAD + q4 * 8];
        }
        f16x8 bf[4];
#pragma unroll
        for (int ni = 0; ni < 4; ++ni) {
            int brow = wn * 64 + ni * 16 + ln;
            bf[ni] = *(const f16x8*)&Bsh[buf][brow * LPAD + q4 * 8];
        }
#pragma unroll
        for (int mi = 0; mi < 2; ++mi)
#pragma unroll
            for (int ni = 0; ni < 4; ++ni)
                acc[mi][ni] = __builtin_amdgcn_mfma_f32_16x16x32_f16(af[mi], bf[ni], acc[mi][ni], 0, 0, 0);
    }

    // ---- epilogue ----  C/D layout: col = ln, row = q4*4 + r  (m89/m91)
#pragma unroll
    for (int ni = 0; ni < 4; ++ni) {
        int col = n0 + wn * 64 + ni * 16 + ln;
        float vb = bias ? bias[col] : 0.0f;
        float s = 0.0f, s2 = 0.0f;
#pragma unroll
        for (int mi = 0; mi < 2; ++mi) {
#pragma unroll
            for (int r = 0; r < 4; ++r) {
                int row_g = m0 + wm * 32 + mi * 16 + q4 * 4 + r;
                float v = acc[mi][ni][r] + vb;
                C[(size_t)row_g * ldc + col] = (OT)v;
                s += v; s2 += v * v;
            }
        }
        if (FUSE_STATS) {
            s  += __shfl_xor(s, 16);  s  += __shfl_xor(s, 32);
            s2 += __shfl_xor(s2, 16); s2 += __shfl_xor(s2, 32);
            if (q4 == 0) {
                atomicAdd(&sumO[col], s);
                atomicAdd(&sqO[col], s2);
            }
        }
    }
}

// ---------------------------------------------------------------------------
// Dedicated interp + bias + BN1-stats kernel.
// y1[m, :] = temp[m, :] + wa*P2[ia, :] + wb*P2[ib, :] + wc*P2[ic, :] + b1
// ---------------------------------------------------------------------------
__global__ __launch_bounds__(256, 8) void interp_stats_kernel(
    const float* __restrict__ temp,     // [MTOT x C1] fp32 gemm result
    const _Float16* __restrict__ P2,    // [BB*SS x C1] f16
    const int* __restrict__ idx3, const float* __restrict__ w3,
    const float* __restrict__ bias,
    _Float16* __restrict__ Y,           // [MTOT x C1] f16
    float* __restrict__ sumO, float* __restrict__ sqO)
{
    __shared__ float sred[2 * C1];      // 512 floats: [sum | sumsq]
    const int tid = threadIdx.x;
    const int sl  = tid & 31;           // col slice (8 cols)
    const int rg  = tid >> 5;           // 0..7
    const int m0  = blockIdx.x * 32;

    sred[tid] = 0.0f; sred[tid + 256] = 0.0f;
    __syncthreads();

    float bv[8];
    *(float4*)&bv[0] = *(const float4*)(bias + sl * 8);
    *(float4*)&bv[4] = *(const float4*)(bias + sl * 8 + 4);

    float sAcc[8]  = {0.f,0.f,0.f,0.f,0.f,0.f,0.f,0.f};
    float s2Acc[8] = {0.f,0.f,0.f,0.f,0.f,0.f,0.f,0.f};

#pragma unroll
    for (int rr = 0; rr < 4; ++rr) {
        const int row = m0 + rg * 4 + rr;
        const int*   ip = idx3 + (size_t)row * 3;
        const float* wp = w3   + (size_t)row * 3;
        int   ia = ip[0], ib = ip[1], ic = ip[2];
        float wa = wp[0], wb = wp[1], wc = wp[2];

        float av[8];
        const float* tp = temp + (size_t)row * C1 + sl * 8;
        *(float4*)&av[0] = *(const float4*)tp;
        *(float4*)&av[4] = *(const float4*)(tp + 4);
        f16x8 pa = *(const f16x8*)(P2 + (size_t)ia * C1 + sl * 8);
        f16x8 pb = *(const f16x8*)(P2 + (size_t)ib * C1 + sl * 8);
        f16x8 pc = *(const f16x8*)(P2 + (size_t)ic * C1 + sl * 8);

        f16x8 outv;
#pragma unroll
        for (int i = 0; i < 8; ++i) {
            float v = av[i];
            v += wa * (float)pa[i];
            v += wb * (float)pb[i];
            v += wc * (float)pc[i];
            v += bv[i];
            outv[i] = (_Float16)v;
            sAcc[i]  += v;
            s2Acc[i] += v * v;
        }
        *(f16x8*)(Y + (size_t)row * C1 + sl * 8) = outv;
    }

#pragma unroll
    for (int i = 0; i < 8; ++i) {
        atomicAdd(&sred[sl * 8 + i],       sAcc[i]);
        atomicAdd(&sred[256 + sl * 8 + i], s2Acc[i]);
    }
    __syncthreads();
    atomicAdd(&sumO[tid], sred[tid]);
    atomicAdd(&sqO[tid],  sred[tid + 256]);
}

// ---------------------------------------------------------------------------
__global__ void finalize_kernel(
    const float* __restrict__ sum, const float* __restrict__ sumsq,
    const float* __restrict__ g, const float* __restrict__ beta,
    int M, int C, float* __restrict__ scale, float* __restrict__ shift)
{
    int c = threadIdx.x;
    if (c >= C) return;
    float invM = 1.0f / (float)M;
    float mean = sum[c] * invM;
    float var = fmaxf(sumsq[c] * invM - mean * mean, 0.0f);
    float rstd = 1.0f / sqrtf(var + 1e-5f);
    float sc = g[c] * rstd;
    scale[c] = sc;
    shift[c] = beta[c] - mean * sc;
}

__global__ __launch_bounds__(256) void bnrelu_kernel(
    float* __restrict__ X, int total4, int C,
    const float* __restrict__ scale, const float* __restrict__ shift)
{
    int i = blockIdx.x * 256 + threadIdx.x;
    if (i >= total4) return;
    float4 v = ((const float4*)X)[i];
    int c = (i * 4) & (C - 1);      // C pow2, 4 | C -> no wrap within the 4
    v.x = fmaxf(v.x * scale[c+0] + shift[c+0], 0.0f);
    v.y = fmaxf(v.y * scale[c+1] + shift[c+1], 0.0f);
    v.z = fmaxf(v.z * scale[c+2] + shift[c+2], 0.0f);
    v.w = fmaxf(v.w * scale[c+3] + shift[c+3], 0.0f);
    ((float4*)X)[i] = v;
}

// ---------------------------------------------------------------------------
extern "C" void kernel_launch(void* const* d_in, const int* in_sizes, int n_in,
                              void* d_out, int out_size, void* d_ws, size_t ws_size,
                              hipStream_t stream) {
    const float* xyz1    = (const float*)d_in[0];
    const float* xyz2    = (const float*)d_in[1];
    const float* points1 = (const float*)d_in[2];
    const float* points2 = (const float*)d_in[3];
    const float* W1      = (const float*)d_in[4];
    const float* b1      = (const float*)d_in[5];
    const float* g1      = (const float*)d_in[6];
    const float* beta1   = (const float*)d_in[7];
    const float* W2      = (const float*)d_in[8];
    const float* b2      = (const float*)d_in[9];
    const float* g2      = (const float*)d_in[10];
    const float* beta2   = (const float*)d_in[11];
    float* out = (float*)d_out;

    // ws layout (byte offsets, 16B-aligned)
    char* ws = (char*)d_ws;
    size_t off = 0;
    int*   idx = (int*)(ws + off);            off += (size_t)MTOT*3*4;
    float* w   = (float*)(ws + off);          off += (size_t)MTOT*3*4;
    _Float16* P2h = (_Float16*)(ws + off);    off += (size_t)BB*SS*C1*2;    // 8 MB
    _Float16* y1h = (_Float16*)(ws + off);    off += (size_t)MTOT*C1*2;     // 32 MB
    float* stats = (float*)(ws + off);        off += 2048*4;
    float* sum1 = stats;            // 256
    float* sq1  = stats + 256;      // 256
    float* sum2 = stats + 512;      // 128
    float* sq2  = stats + 640;      // 128
    float* scale1 = stats + 768;    // 256
    float* shift1 = stats + 1024;   // 256
    float* scale2 = stats + 1280;   // 128
    float* shift2 = stats + 1408;   // 128
    float4* packed = (float4*)(ws + off);     off += (size_t)BB*SS*16;      // 1 MB
    _Float16* W1c = (_Float16*)(ws + off);    off += (size_t)C1*(D1+D2)*2;
    _Float16* W2c = (_Float16*)(ws + off);    off += (size_t)C2*C1*2;
    off = (off + 255) & ~(size_t)255;
    float* tempf = (float*)(ws + off);        off += (size_t)MTOT*C1*4;     // 64 MB
    // knn partials: 6 SoA planes of NCH*MTOT (25.2 MB total) alias the y1h
    // region (32 MB; y1h is written later, by interp_stats_kernel)
    float* pd0 = (float*)y1h;                 // NCH*MTOT floats (4.2 MB each)
    float* pd1 = pd0 + (size_t)NCH*MTOT;
    float* pd2 = pd1 + (size_t)NCH*MTOT;
    int*   pi0 = (int*)(pd2 + (size_t)NCH*MTOT);
    int*   pi1 = pi0 + (size_t)NCH*MTOT;
    int*   pi2 = pi1 + (size_t)NCH*MTOT;

    hipMemsetAsync(stats, 0, 768 * sizeof(float), stream);

    pack_kernel<<<(BB*SS)/256, 256, 0, stream>>>(xyz2, packed);
    wcvt_kernel<<<(C1*(D1+D2))/256, 256, 0, stream>>>(W1, W2, W1c, W2c);

    knn3_partial_kernel<<<BB * (NN/(PTH*QPT)) * NCH, PTH, 0, stream>>>(
        xyz1, packed, pd0, pd1, pd2, pi0, pi1, pi2);
    knn3_merge_kernel<<<MTOT/256, 256, 0, stream>>>(
        pd0, pd1, pd2, pi0, pi1, pi2, idx, w);

    // P2 = points2 @ W1[:,128:]^T   [B*S x 256], K=256, f16 out
    gemm_mfma_kernel<256, float, _Float16, false, false>
        <<<dim3((BB*SS)/64, C1/128), 256, 0, stream>>>(
        points2, D2, W1c + D1, D1 + D2, P2h, C1,
        nullptr, nullptr, nullptr, nullptr, nullptr);

    // temp = points1 @ W1[:,:128]^T   (plain GEMM, fp32 out, no fusion)
    gemm_mfma_kernel<128, float, float, false, false>
        <<<dim3(MTOT/64, C1/128), 256, 0, stream>>>(
        points1, D1, W1c, D1 + D2, tempf, C1,
        nullptr, nullptr, nullptr, nullptr, nullptr);

    // y1 = temp + interp(P2) + b1  (f16 out) + BN1 stats from fp32
    interp_stats_kernel<<<MTOT/32, 256, 0, stream>>>(
        tempf, P2h, idx, w, b1, y1h, sum1, sq1);

    finalize_kernel<<<1, 256, 0, stream>>>(sum1, sq1, g1, beta1, MTOT, C1, scale1, shift1);

    // out = relu(bn1(y1)) @ W2^T + b2;  fp32 out; fused BN2 stats
    gemm_mfma_kernel<256, _Float16, float, true, true>
        <<<dim3(MTOT/64, C2/128), 256, 0, stream>>>(
        y1h, C1, W2c, C1, out, C2,
        b2, scale1, shift1, sum2, sq2);

    finalize_kernel<<<1, 128, 0, stream>>>(sum2, sq2, g2, beta2, MTOT, C2, scale2, shift2);
    bnrelu_kernel<<<(MTOT*C2/4)/256, 256, 0, stream>>>(out, MTOT*C2/4, C2, scale2, shift2);
}